// Round 3
// baseline (51.597 us; speedup 1.0000x reference)
//
#include <hip/hip_runtime.h>

// Chamfer distance, B=8, N=M=4096, fp32.
// loss = (1/(B*N)) * sum over 2*B*N slots of sqrt(min_d2)
//
// K0 (cd_prep):   build float4 table (x,y,z,|p|^2) for both clouds; zero hdr.
// K1 (cd_partial): per (qblk, chunk, dirb) block: 2048 queries x 128 db points,
//                  db read wave-uniformly (s_load -> SGPR), pure-VALU inner loop,
//                  partial mins to P (no atomics, deterministic).
// K2 (cd_reduce): per-slot min over 32 chunks, +|q|^2, sqrt, deterministic
//                  fixed-point u64 atomic sum; last block writes the loss.

#define BATCH 8
#define NPTS 4096
#define THREADS 256
#define TQ 8
#define QB (TQ*THREADS)        // 2048 queries per block
#define QBLKS (NPTS/QB)        // 2
#define CHUNKS 32
#define CHUNK (NPTS/CHUNKS)    // 128 db points per chunk
#define NSLOT (2*BATCH*NPTS)   // 65536
#define NCLOUD (BATCH*NPTS)    // 32768 points per cloud
#define FIX_SCALE 4294967296.0 // 2^32

__global__ __launch_bounds__(256) void cd_prep(
        const float* __restrict__ pred,
        const float* __restrict__ targ,
        float4* __restrict__ pts4,
        unsigned long long* __restrict__ hdr) {
    int i = blockIdx.x * 256 + threadIdx.x;   // 0..2*NCLOUD-1
    if (i == 0) { hdr[0] = 0ull; hdr[1] = 0ull; }
    const float* src = (i < NCLOUD) ? pred : targ;
    int idx = (i < NCLOUD) ? i : i - NCLOUD;
    const float* p = src + (size_t)idx * 3;
    float x = p[0], y = p[1], z = p[2];
    pts4[i] = make_float4(x, y, z, fmaf(x, x, fmaf(y, y, z * z)));
}

__global__ __launch_bounds__(THREADS, 4) void cd_partial(
        const float4* __restrict__ pts4,
        float* __restrict__ P) {
    const int qblk  = blockIdx.x;      // 0..QBLKS-1
    const int chunk = blockIdx.y;      // 0..CHUNKS-1
    const int dirb  = blockIdx.z;      // dir*BATCH + b
    const int dir   = dirb >> 3;
    const int b     = dirb & 7;
    const int tid   = threadIdx.x;

    // query cloud: dir==0 -> pred (cloud 0); db cloud: dir==0 -> targ (cloud 1)
    const float4* Q  = pts4 + (dir ? NCLOUD : 0) + (size_t)b * NPTS;
    const float4* Db = pts4 + (dir ? 0 : NCLOUD) + (size_t)b * NPTS
                            + (size_t)chunk * CHUNK;   // block-uniform base

    float qx[TQ], qy[TQ], qz[TQ], m[TQ];
    const int q0 = qblk * QB + tid;
    #pragma unroll
    for (int k = 0; k < TQ; ++k) {
        float4 qp = Q[q0 + k * THREADS];
        qx[k] = -2.f * qp.x; qy[k] = -2.f * qp.y; qz[k] = -2.f * qp.z;
        m[k]  = __uint_as_float(0x7F800000u);
    }

    #pragma unroll 2
    for (int j = 0; j < CHUNK; j += 4) {
        // wave-uniform loads -> scalar regs (s_load), constant-cache resident
        float4 b0 = Db[j], b1 = Db[j + 1], b2 = Db[j + 2], b3 = Db[j + 3];
        #pragma unroll
        for (int k = 0; k < TQ; ++k) {
            float t0 = fmaf(qx[k], b0.x, fmaf(qy[k], b0.y, fmaf(qz[k], b0.z, b0.w)));
            float t1 = fmaf(qx[k], b1.x, fmaf(qy[k], b1.y, fmaf(qz[k], b1.z, b1.w)));
            float t2 = fmaf(qx[k], b2.x, fmaf(qy[k], b2.y, fmaf(qz[k], b2.z, b2.w)));
            float t3 = fmaf(qx[k], b3.x, fmaf(qy[k], b3.y, fmaf(qz[k], b3.z, b3.w)));
            float u  = fminf(fminf(t0, t1), t2);   // v_min3_f32
            m[k] = fminf(fminf(m[k], u), t3);      // v_min3_f32
        }
    }

    float* out = P + (size_t)chunk * NSLOT + (size_t)dirb * NPTS + q0;
    #pragma unroll
    for (int k = 0; k < TQ; ++k) out[k * THREADS] = m[k];
}

__global__ __launch_bounds__(256) void cd_reduce(
        const float4* __restrict__ pts4,
        const float* __restrict__ P,
        unsigned long long* __restrict__ hdr,
        float* __restrict__ out) {
    const int tid  = threadIdx.x;
    const int slot = blockIdx.x * 256 + tid;   // 0..NSLOT-1
    const int dirb = slot >> 12;
    const int q    = slot & (NPTS - 1);
    const int dir  = dirb >> 3;
    const int b    = dirb & 7;

    float nq = pts4[(dir ? NCLOUD : 0) + (size_t)b * NPTS + q].w;

    float m = __uint_as_float(0x7F800000u);
    #pragma unroll
    for (int c = 0; c < CHUNKS; c += 2)
        m = fminf(m, fminf(P[(size_t)c * NSLOT + slot],
                           P[(size_t)(c + 1) * NSLOT + slot]));

    float d = sqrtf(fmaxf(nq + m, 0.f));

    float s = d;
    #pragma unroll
    for (int off = 32; off > 0; off >>= 1) s += __shfl_down(s, off);
    __shared__ float wsum[4];
    if ((tid & 63) == 0) wsum[tid >> 6] = s;
    __syncthreads();

    if (tid == 0) {
        float bs = wsum[0] + wsum[1] + wsum[2] + wsum[3];
        unsigned long long fx = (unsigned long long)((double)bs * FIX_SCALE);
        atomicAdd(hdr, fx);
        __threadfence();
        unsigned int old = atomicAdd((unsigned int*)(hdr + 1), 1u);
        if (old == gridDim.x - 1) {
            unsigned long long tot = atomicAdd(hdr, 0ull);
            out[0] = (float)(((double)tot / FIX_SCALE) / (double)(BATCH * NPTS));
        }
    }
}

extern "C" void kernel_launch(void* const* d_in, const int* in_sizes, int n_in,
                              void* d_out, int out_size, void* d_ws, size_t ws_size,
                              hipStream_t stream) {
    const float* pred = (const float*)d_in[0];
    const float* targ = (const float*)d_in[1];
    unsigned long long* hdr = (unsigned long long*)d_ws;                 // 16 B
    float* P     = (float*)((char*)d_ws + 64);                           // 8 MB
    float4* pts4 = (float4*)((char*)d_ws + 64 + (size_t)CHUNKS * NSLOT * 4); // 1 MB
    float* out   = (float*)d_out;

    cd_prep<<<2 * NCLOUD / 256, 256, 0, stream>>>(pred, targ, pts4, hdr);
    cd_partial<<<dim3(QBLKS, CHUNKS, 2 * BATCH), THREADS, 0, stream>>>(pts4, P);
    cd_reduce<<<NSLOT / 256, 256, 0, stream>>>(pts4, P, hdr, out);
}